// Round 13
// baseline (183.657 us; speedup 1.0000x reference)
//
#include <hip/hip_runtime.h>
#include <hip/hip_bf16.h>

typedef __attribute__((ext_vector_type(4))) float f32x4;
typedef __attribute__((ext_vector_type(8))) short bf16x8;

#define MFMA16(a, b, c) __builtin_amdgcn_mfma_f32_16x16x32_bf16(a, b, c, 0, 0, 0)

constexpr int BATCH = 4;
constexpr int SEQ   = 2048;
constexpr int DIM   = 1024;

__device__ __forceinline__ ushort f2b(float f) {
  __hip_bfloat16 h = __float2bfloat16(f);
  union { __hip_bfloat16 h; ushort u; } cv; cv.h = h; return cv.u;
}

// ---------------- fused fp32 -> bf16 convert ----------------
__global__ __launch_bounds__(256) void cvt_all(
    const float* __restrict__ x, const float* __restrict__ wq,
    const float* __restrict__ wk, const float* __restrict__ wv,
    ushort* __restrict__ xb, ushort* __restrict__ wb) {
  int i = blockIdx.x * 256 + threadIdx.x;
  const float* src; ushort* dst; int off;
  if (i < 2097152) { src = x; dst = xb; off = i; }
  else {
    int j = i - 2097152;
    int s = j >> 18;
    off = j & 262143;
    src = (s == 0) ? wq : (s == 1) ? wk : wv;
    dst = wb + s * 1048576;
  }
  float4 v = reinterpret_cast<const float4*>(src)[off];
  ushort4 o;
  o.x = f2b(v.x); o.y = f2b(v.y); o.z = f2b(v.z); o.w = f2b(v.w);
  reinterpret_cast<ushort4*>(dst)[off] = o;
}

__device__ __forceinline__ void gload_lds16(const void* g, void* l) {
  __builtin_amdgcn_global_load_lds(
      (const __attribute__((address_space(1))) unsigned int*)g,
      (__attribute__((address_space(3))) unsigned int*)l, 16, 0, 0);
}

#define VWAIT(n) asm volatile("s_waitcnt vmcnt(" #n ")" ::: "memory")
#define BAR() __builtin_amdgcn_s_barrier()

// ====== 256x256 8-wave GEMM: 2.5-buffer, single-barrier, wave-staggered ======
// A ring x3, B ring x2 (full 32KB tiles) = 160 KiB LDS exactly.
// Per K-tile(64): VWAIT(4) [drains A(t),B(t); leaves A(t+1)] ; BAR ;
//   staggered {reads, stage B(t+1)+A(t+2), MFMA}.
// Stagger: wm=0 waves run quadrants Q1,Q2,Q3,Q4; wm=1 run Q3,Q4,Q1,Q2.
// SIMD k hosts waves k(wm0) + k+4(wm1) -> one wave's ds_reads overlap the
// other's MFMAs (breaks the read-burst/MFMA-burst phase-lock).
// MODE 0 (QK): routed by seg=n0>>10 to C0/C1 + bias, bf16 out.
// MODE 1 (S): SWAPPED mfma; P=exp(scale*acc) ushort4 stores + lpart sums.
template <int MODE>
__device__ __forceinline__ void gemm256_body(
    const ushort* __restrict__ Ag, const ushort* __restrict__ Bg,
    void* __restrict__ C0, void* __restrict__ C1,
    const float* __restrict__ b0, const float* __restrict__ b1,
    float* __restrict__ lpart,
    int N, int Kd, float scale, long sA, long sB, long sC)
{
  constexpr int TSZ = 256 * 64;            // ushorts per full operand tile
  __shared__ ushort SH[5 * TSZ];           // A ring 3 | B ring 2 = 160 KiB

  int nwg = gridDim.x * gridDim.y;
  int id = blockIdx.y * gridDim.x + blockIdx.x;
  int swz = (nwg & 7) ? id : ((id & 7) * (nwg >> 3) + (id >> 3));
  const int m0 = (swz / gridDim.x) * 256;
  const int n0 = (swz % gridDim.x) * 256;
  const int bz = blockIdx.z;
  const char* Ab = (const char*)(Ag + (size_t)bz * sA);
  const char* Bb = (const char*)(Bg + (size_t)bz * sB);
  const int t = threadIdx.x;
  const int lane = t & 63;
  const int w = t >> 6;
  const int wm = w >> 2, wn = w & 3;       // 2M x 4N, wave = 128 x 64
  const size_t pA = (size_t)Kd * 2;
  const size_t pB = (size_t)Kd * 2;
  const int nt = Kd >> 6;

  auto stageH = [&](ushort* ldsb, const char* gb, size_t pitch) {
#pragma unroll
    for (int j = 0; j < 2; ++j) {
      int g = j * 512 + t;
      int r = g >> 3;
      int cb = ((g & 7) << 4) ^ ((r & 7) << 4);
      gload_lds16(gb + (size_t)r * pitch + cb,
                  (char*)ldsb + (size_t)((j * 512 + (t & ~63)) << 4));
    }
  };
  auto ldfrag = [&](const ushort* base, int row, int ks) -> bf16x8 {
    int L = row * 128 + ks * 64 + ((lane >> 4) << 4);
    return *(const bf16x8*)((const char*)base + (L ^ ((row & 7) << 4)));
  };
  auto stageA = [&](int tile) {            // 4 loads/thread
    ushort* buf = SH + (tile % 3) * TSZ;
    const size_t ko = (size_t)tile * 128;
    stageH(buf, Ab + (size_t)m0 * pA + ko, pA);
    stageH(buf + 128 * 64, Ab + (size_t)(m0 + 128) * pA + ko, pA);
  };
  auto stageB = [&](int tile) {            // 4 loads/thread
    ushort* buf = SH + (3 + (tile & 1)) * TSZ;
    const size_t ko = (size_t)tile * 128;
    stageH(buf, Bb + (size_t)n0 * pB + ko, pB);
    stageH(buf + 128 * 64, Bb + (size_t)(n0 + 128) * pB + ko, pB);
  };

  f32x4 acc[8][4];
#pragma unroll
  for (int i = 0; i < 8; ++i)
#pragma unroll
    for (int j = 0; j < 4; ++j) acc[i][j] = 0.f;

  bf16x8 a[4][2];   // current m-half frags (4 x 2 ks)
  bf16x8 b[4][2];   // all 4 n-frags x 2 ks

// read b-frags of n-half H (4 ds_read)
#define RDB(H)                                                           \
  _Pragma("unroll") for (int ni = 0; ni < 2; ++ni) {                     \
    int r = wn * 64 + ((H) * 2 + ni) * 16 + (lane & 15);                 \
    b[(H) * 2 + ni][0] = ldfrag(Bc, r, 0);                               \
    b[(H) * 2 + ni][1] = ldfrag(Bc, r, 1);                               \
  }
// read a-frags of m-half H (8 ds_read)
#define RDA(H)                                                           \
  _Pragma("unroll") for (int mi = 0; mi < 4; ++mi) {                     \
    int r = wm * 128 + ((H) * 4 + mi) * 16 + (lane & 15);                \
    a[mi][0] = ldfrag(Ac, r, 0);                                         \
    a[mi][1] = ldfrag(Ac, r, 1);                                         \
  }
// MFMA quadrant (m-half MH x n-half NH): 16 MFMA
#define MF(MH, NH)                                                       \
  __builtin_amdgcn_s_setprio(1);                                         \
  _Pragma("unroll") for (int mi = 0; mi < 4; ++mi)                       \
      _Pragma("unroll") for (int ni = 0; ni < 2; ++ni) {                 \
    if constexpr (MODE == 1) {                                           \
      acc[(MH) * 4 + mi][(NH) * 2 + ni] = MFMA16(                        \
          b[(NH) * 2 + ni][0], a[mi][0], acc[(MH) * 4 + mi][(NH) * 2 + ni]); \
      acc[(MH) * 4 + mi][(NH) * 2 + ni] = MFMA16(                        \
          b[(NH) * 2 + ni][1], a[mi][1], acc[(MH) * 4 + mi][(NH) * 2 + ni]); \
    } else {                                                             \
      acc[(MH) * 4 + mi][(NH) * 2 + ni] = MFMA16(                        \
          a[mi][0], b[(NH) * 2 + ni][0], acc[(MH) * 4 + mi][(NH) * 2 + ni]); \
      acc[(MH) * 4 + mi][(NH) * 2 + ni] = MFMA16(                        \
          a[mi][1], b[(NH) * 2 + ni][1], acc[(MH) * 4 + mi][(NH) * 2 + ni]); \
    }                                                                    \
  }                                                                      \
  __builtin_amdgcn_s_setprio(0);
#define STG()                                                            \
  if (tt + 1 < nt) stageB(tt + 1);                                       \
  if (tt + 2 < nt) stageA(tt + 2);

  // ---- prologue: B(0), A(0), A(1) ----
  stageB(0);
  stageA(0);
  stageA(1);

  for (int tt = 0; tt < nt; ++tt) {
    const ushort* Ac = SH + (tt % 3) * TSZ;
    const ushort* Bc = SH + (3 + (tt & 1)) * TSZ;
    if (tt + 1 < nt) VWAIT(4);   // drains A(t),B(t); leaves A(t+1) in flight
    else VWAIT(0);
    BAR();                       // publish: every wave drained its t-loads
    __builtin_amdgcn_sched_barrier(0);
    if (wm == 0) {
      RDB(0); RDA(0); STG();
      MF(0, 0);
      RDB(1);
      MF(0, 1);
      RDA(1);
      MF(1, 1);
      MF(1, 0);
    } else {
      RDB(1); RDA(1); STG();
      MF(1, 1);
      RDB(0);
      MF(1, 0);
      RDA(0);
      MF(0, 0);
      MF(0, 1);
    }
  }
#undef RDB
#undef RDA
#undef MF
#undef STG

  if constexpr (MODE == 0) {
    const int seg = n0 >> 10;
    const int n0l = n0 & 1023;
    const float* biasp = seg == 0 ? b0 : b1;
    ushort* Ch = (ushort*)(seg == 0 ? C0 : C1);
#pragma unroll
    for (int mf = 0; mf < 8; ++mf)
#pragma unroll
      for (int nf = 0; nf < 4; ++nf) {
        int gn = n0l + wn * 64 + nf * 16 + (lane & 15);
        float bb = biasp[gn];
#pragma unroll
        for (int r = 0; r < 4; ++r) {
          int gm = m0 + wm * 128 + mf * 16 + (lane >> 4) * 4 + r;
          Ch[(size_t)gm * N + gn] = f2b(acc[mf][nf][r] * scale + bb);
        }
      }
  } else {
    // S (swapped): lane row gm fixed per mf; 4 consecutive gn per reg.
    ushort* Ch = (ushort*)C0 + (size_t)bz * sC;
    float rs[8];
#pragma unroll
    for (int mf = 0; mf < 8; ++mf) rs[mf] = 0.f;
#pragma unroll
    for (int mf = 0; mf < 8; ++mf) {
      int gm = m0 + wm * 128 + mf * 16 + (lane & 15);
#pragma unroll
      for (int nf = 0; nf < 4; ++nf) {
        int gn0 = n0 + wn * 64 + nf * 16 + (lane >> 4) * 4;
        float e0 = __expf(acc[mf][nf][0] * scale);
        float e1 = __expf(acc[mf][nf][1] * scale);
        float e2 = __expf(acc[mf][nf][2] * scale);
        float e3 = __expf(acc[mf][nf][3] * scale);
        rs[mf] += (e0 + e1) + (e2 + e3);
        ushort4 pk;
        pk.x = f2b(e0); pk.y = f2b(e1); pk.z = f2b(e2); pk.w = f2b(e3);
        *(ushort4*)&Ch[(size_t)gm * N + gn0] = pk;
      }
      rs[mf] += __shfl_xor(rs[mf], 16);
      rs[mf] += __shfl_xor(rs[mf], 32);
    }
    __syncthreads();
    float* Lred = (float*)SH;              // [4 wn][256 rows]
#pragma unroll
    for (int mf = 0; mf < 8; ++mf)
      if (lane < 16) Lred[wn * 256 + wm * 128 + mf * 16 + lane] = rs[mf];
    __syncthreads();
    if (t < 256) {
      float s = Lred[t] + Lred[256 + t] + Lred[512 + t] + Lred[768 + t];
      lpart[((size_t)bz * SEQ + m0 + t) * 8 + (n0 >> 8)] = s;
    }
  }
}

__global__ __launch_bounds__(512) void gemm_qk(
    const ushort* __restrict__ Ag, const ushort* __restrict__ Bg,
    void* __restrict__ C0, void* __restrict__ C1,
    const float* __restrict__ b0, const float* __restrict__ b1) {
  gemm256_body<0>(Ag, Bg, C0, C1, b0, b1, nullptr, DIM, DIM, 1.0f, 0, 0, 0);
}
__global__ __launch_bounds__(512) void gemm_s(
    const ushort* __restrict__ Ag, const ushort* __restrict__ Bg,
    void* __restrict__ C0, float* __restrict__ lpart) {
  gemm256_body<1>(Ag, Bg, C0, nullptr, nullptr, nullptr, lpart,
                  SEQ, DIM, 0.03125f, (long)SEQ * DIM, (long)SEQ * DIM,
                  (long)SEQ * SEQ);
}

// ====== 128x256 8-wave TRIPLE-BUFFERED GEMM (2Mx4N, wave 64x64) ======
// (round-9..12 proven body, UNCHANGED this round)
// BAR1 (WAR) / stage t+2 / VWAIT(12) / BAR2 (RAW) / reads + MFMA.
// MODE 2 (V): unswapped; out transposed to vt[b][d][token] via LDS bounce.
// MODE 3 (PV): SWAPPED mfma; f32x4 coalesced stores, 1 inv/row.
template <int MODE>
__device__ __forceinline__ void gemm_small_body(
    const ushort* __restrict__ Ag, const ushort* __restrict__ Bg,
    void* __restrict__ C0, const float* __restrict__ x0,
    int N, int Kd, long sA, long sB, long sC)
{
  constexpr int ASZ = 128 * 64;
  constexpr int BSZ = 256 * 64;
  __shared__ ushort SH[3 * ASZ + 3 * BSZ]; // 144 KiB

  int nwg = gridDim.x * gridDim.y;
  int id = blockIdx.y * gridDim.x + blockIdx.x;
  int swz = (nwg & 7) ? id : ((id & 7) * (nwg >> 3) + (id >> 3));
  const int m0 = (swz / gridDim.x) * 128;
  const int n0 = (swz % gridDim.x) * 256;
  const int bz = blockIdx.z;
  const char* Ab = (const char*)(Ag + (size_t)bz * sA);
  const char* Bb = (const char*)(Bg + (size_t)bz * sB);
  const int t = threadIdx.x;
  const int lane = t & 63;
  const int w = t >> 6;
  const int wm = w >> 2, wn = w & 3;       // 2M x 4N, wave = 64 x 64
  const size_t pA = (size_t)Kd * 2;
  const size_t pB = (size_t)Kd * 2;
  const int nt = Kd >> 6;

  auto stageH = [&](ushort* ldsb, const char* gb, size_t pitch) {
#pragma unroll
    for (int j = 0; j < 2; ++j) {
      int g = j * 512 + t;
      int r = g >> 3;
      int cb = ((g & 7) << 4) ^ ((r & 7) << 4);
      gload_lds16(gb + (size_t)r * pitch + cb,
                  (char*)ldsb + (size_t)((j * 512 + (t & ~63)) << 4));
    }
  };
  auto ldfrag = [&](const ushort* base, int row, int ks) -> bf16x8 {
    int L = row * 128 + ks * 64 + ((lane >> 4) << 4);
    return *(const bf16x8*)((const char*)base + (L ^ ((row & 7) << 4)));
  };
  auto stageT = [&](int tile) {
    ushort* Abuf = SH + (tile % 3) * ASZ;
    ushort* Bbuf = SH + 3 * ASZ + (tile % 3) * BSZ;
    const size_t ko = (size_t)tile * 128;
    stageH(Abuf, Ab + (size_t)m0 * pA + ko, pA);
    stageH(Bbuf, Bb + (size_t)n0 * pB + ko, pB);
    stageH(Bbuf + 128 * 64, Bb + (size_t)(n0 + 128) * pB + ko, pB);
  };

  f32x4 acc[4][4];
#pragma unroll
  for (int i = 0; i < 4; ++i)
#pragma unroll
    for (int j = 0; j < 4; ++j) acc[i][j] = 0.f;

  bf16x8 a[2][2];
  bf16x8 b[4][2];

  stageT(0);
  stageT(1);

  for (int tt = 0; tt < nt; ++tt) {
    const ushort* Ac = SH + (tt % 3) * ASZ;
    const ushort* Bc = SH + 3 * ASZ + (tt % 3) * BSZ;
    BAR();
    if (tt + 2 < nt) { stageT(tt + 2); VWAIT(12); }
    else if (tt + 1 < nt) VWAIT(6);
    else VWAIT(0);
    BAR();
#pragma unroll
    for (int nf = 0; nf < 4; ++nf) {
      int r = wn * 64 + nf * 16 + (lane & 15);
      b[nf][0] = ldfrag(Bc, r, 0);
      b[nf][1] = ldfrag(Bc, r, 1);
    }
#pragma unroll
    for (int g = 0; g < 2; ++g) {
#pragma unroll
      for (int i = 0; i < 2; ++i) {
        int r = wm * 64 + (g * 2 + i) * 16 + (lane & 15);
        a[i][0] = ldfrag(Ac, r, 0);
        a[i][1] = ldfrag(Ac, r, 1);
      }
      __builtin_amdgcn_s_setprio(1);
#pragma unroll
      for (int i = 0; i < 2; ++i)
#pragma unroll
        for (int nf = 0; nf < 4; ++nf) {
          if constexpr (MODE == 3) {
            acc[g * 2 + i][nf] = MFMA16(b[nf][0], a[i][0], acc[g * 2 + i][nf]);
            acc[g * 2 + i][nf] = MFMA16(b[nf][1], a[i][1], acc[g * 2 + i][nf]);
          } else {
            acc[g * 2 + i][nf] = MFMA16(a[i][0], b[nf][0], acc[g * 2 + i][nf]);
            acc[g * 2 + i][nf] = MFMA16(a[i][1], b[nf][1], acc[g * 2 + i][nf]);
          }
        }
      __builtin_amdgcn_s_setprio(0);
    }
  }

  if constexpr (MODE == 2) {
    __syncthreads();
    const int b_ = m0 >> 11;
    const int tok0 = m0 & 2047;
    ushort* vtb = (ushort*)C0 + (size_t)b_ * DIM * SEQ;
    ushort* T = SH;                        // [256 d][132 tok]
    {
#pragma unroll
      for (int nf = 0; nf < 4; ++nf) {
        int d_loc = wn * 64 + nf * 16 + (lane & 15);
        float bvv = x0[n0 + d_loc];
#pragma unroll
        for (int mf = 0; mf < 4; ++mf) {
          int tok = wm * 64 + mf * 16 + (lane >> 4) * 4;
          ushort4 pk;
          pk.x = f2b(acc[mf][nf][0] + bvv);
          pk.y = f2b(acc[mf][nf][1] + bvv);
          pk.z = f2b(acc[mf][nf][2] + bvv);
          pk.w = f2b(acc[mf][nf][3] + bvv);
          *(ushort4*)&T[d_loc * 132 + tok] = pk;
        }
      }
    }
    __syncthreads();
    {
      int rr = t >> 1, ch = t & 1;
      ushort* dst = vtb + (size_t)(n0 + rr) * SEQ + tok0 + ch * 64;
#pragma unroll
      for (int i = 0; i < 8; ++i)
        *(bf16x8*)(dst + i * 8) = *(const bf16x8*)&T[rr * 132 + ch * 64 + i * 8];
    }
  } else {
    const float* lp = x0 + (size_t)bz * SEQ * 8;
    float* Cf = (float*)C0 + (size_t)bz * sC;
#pragma unroll
    for (int mf = 0; mf < 4; ++mf) {
      int row = m0 + wm * 64 + mf * 16 + (lane & 15);
      const f32x4* q = (const f32x4*)(lp + (size_t)row * 8);
      f32x4 u = q[0] + q[1];
      float inv = 1.f / ((u[0] + u[1]) + (u[2] + u[3]));
#pragma unroll
      for (int nf = 0; nf < 4; ++nf) {
        int gn0 = n0 + wn * 64 + nf * 16 + (lane >> 4) * 4;
        f32x4 o = acc[mf][nf] * inv;
        *(f32x4*)&Cf[(size_t)row * N + gn0] = o;
      }
    }
  }
}

__global__ __launch_bounds__(512) void gemm_v(
    const ushort* __restrict__ Ag, const ushort* __restrict__ Bg,
    void* __restrict__ C0, const float* __restrict__ bv) {
  gemm_small_body<2>(Ag, Bg, C0, bv, DIM, DIM, 0, 0, 0);
}
__global__ __launch_bounds__(512) void gemm_pv(
    const ushort* __restrict__ Ag, const ushort* __restrict__ Bg,
    void* __restrict__ C0, const float* __restrict__ lpart) {
  gemm_small_body<3>(Ag, Bg, C0, lpart, DIM, SEQ,
                     (long)SEQ * SEQ, (long)DIM * SEQ, (long)SEQ * DIM);
}

// ---------------- launcher ----------------
extern "C" void kernel_launch(void* const* d_in, const int* in_sizes, int n_in,
                              void* d_out, int out_size, void* d_ws, size_t ws_size,
                              hipStream_t stream) {
  const float* x  = (const float*)d_in[0];
  const float* Wq = (const float*)d_in[1];
  const float* bq = (const float*)d_in[2];
  const float* Wk = (const float*)d_in[3];
  const float* bk = (const float*)d_in[4];
  const float* Wv = (const float*)d_in[5];
  const float* bv = (const float*)d_in[6];
  float* out = (float*)d_out;

  char* ws = (char*)d_ws;
  // ws layout (bytes), total 90.2 MB:
  //   [0, 32M)      SP  [4][2048][2048] bf16 (xb at [16M,32M) dead by then)
  //   [32M, 38.3M)  wb  (dead after gemm_v) / lpart overlay
  //   [38.3M, ...)  qb | kb | vt  (16M each)
  ushort* xb = (ushort*)(ws + 16777216);
  ushort* wb = (ushort*)(ws + 33554432);
  ushort* qb = (ushort*)(ws + 39845888);
  ushort* kb = (ushort*)(ws + 56623104);
  ushort* vt = (ushort*)(ws + 73400320);
  ushort* SP = (ushort*)(ws);
  float* lpart = (float*)(ws + 33554432);  // [4][2048][8] f32, overlays dead wb

  cvt_all<<<11264, 256, 0, stream>>>(x, Wq, Wk, Wv, xb, wb);
  // Q,K: [8192 x 2048] = X . [Wq;Wk]^T + bias.  256 blocks.
  gemm_qk<<<dim3(8, 32, 1), 512, 0, stream>>>(xb, wb, qb, kb, bq, bk);
  // V: [8192 x 1024] = X . Wv^T + bias, transposed to vt.  256 blocks (4x64).
  gemm_v<<<dim3(4, 64, 1), 512, 0, stream>>>(xb, wb + 2097152, vt, bv);
  // P = exp(Q K^T / 32) -> SP (+ row partial sums -> lpart).  256 blocks.
  gemm_s<<<dim3(8, 8, 4), 512, 0, stream>>>(qb, kb, SP, lpart);
  // O = (P V) / rowsum.  256 blocks (4x16x4).
  gemm_pv<<<dim3(4, 16, 4), 512, 0, stream>>>(SP, vt, out, lpart);
}

// Round 14
// 157.238 us; speedup vs baseline: 1.1680x; 1.1680x over previous
//
#include <hip/hip_runtime.h>
#include <hip/hip_bf16.h>

typedef __attribute__((ext_vector_type(4))) float f32x4;
typedef __attribute__((ext_vector_type(8))) short bf16x8;

#define MFMA16(a, b, c) __builtin_amdgcn_mfma_f32_16x16x32_bf16(a, b, c, 0, 0, 0)

constexpr int BATCH = 4;
constexpr int SEQ   = 2048;
constexpr int DIM   = 1024;

__device__ __forceinline__ ushort f2b(float f) {
  __hip_bfloat16 h = __float2bfloat16(f);
  union { __hip_bfloat16 h; ushort u; } cv; cv.h = h; return cv.u;
}

// ---------------- fused fp32 -> bf16 convert ----------------
__global__ __launch_bounds__(256) void cvt_all(
    const float* __restrict__ x, const float* __restrict__ wq,
    const float* __restrict__ wk, const float* __restrict__ wv,
    ushort* __restrict__ xb, ushort* __restrict__ wb) {
  int i = blockIdx.x * 256 + threadIdx.x;
  const float* src; ushort* dst; int off;
  if (i < 2097152) { src = x; dst = xb; off = i; }
  else {
    int j = i - 2097152;
    int s = j >> 18;
    off = j & 262143;
    src = (s == 0) ? wq : (s == 1) ? wk : wv;
    dst = wb + s * 1048576;
  }
  float4 v = reinterpret_cast<const float4*>(src)[off];
  ushort4 o;
  o.x = f2b(v.x); o.y = f2b(v.y); o.z = f2b(v.z); o.w = f2b(v.w);
  reinterpret_cast<ushort4*>(dst)[off] = o;
}

__device__ __forceinline__ void gload_lds16(const void* g, void* l) {
  __builtin_amdgcn_global_load_lds(
      (const __attribute__((address_space(1))) unsigned int*)g,
      (__attribute__((address_space(3))) unsigned int*)l, 16, 0, 0);
}

#define VWAIT(n) asm volatile("s_waitcnt vmcnt(" #n ")" ::: "memory")
#define BAR() __builtin_amdgcn_s_barrier()

// ====== 256x256 8-wave GEMM, m201-faithful 4-phase/K-tile schedule ======
// 2Mx4N waves (wave 128x64). LDS = 8 half-buffers (2 parity x 2 half x A,B)
// = 128 KiB. Per K-tile: 4 phases, each {ds_reads; stage 1 half; BAR;
// setprio 16 MFMA; BAR}. Quadrants Q00,Q10,Q11,Q01 -> A-halves last read
// P1, B-halves P2. Stage stream: P0:B0(t+1) P1:B1(t+1) P2:A0(t+2)
// P3:A1(t+2) (each WAR >= 1 barrier after the buffer's last read).
// VWAIT(4) ONCE per tile at P3 (drains tile t+1 fully; leaves A(t+2) in
// flight - never 0 mid-loop). Prologue: 6 halves + VWAIT(4).
// ds_reads/phase = 12/8/4/0 (matches m201).
// MODE 0 (QK): routed by seg=n0>>10 to C0/C1 + bias, bf16 out.
// MODE 1 (S): SWAPPED mfma; P=exp(scale*acc) ushort4 stores + lpart sums.
template <int MODE>
__device__ __forceinline__ void gemm256_body(
    const ushort* __restrict__ Ag, const ushort* __restrict__ Bg,
    void* __restrict__ C0, void* __restrict__ C1,
    const float* __restrict__ b0, const float* __restrict__ b1,
    float* __restrict__ lpart,
    int N, int Kd, float scale, long sA, long sB, long sC)
{
  constexpr int HSZ = 128 * 64;            // ushorts per half-buffer (16 KB)
  __shared__ ushort SH[8 * HSZ];           // A[2par][2half] | B[2par][2half]

  int nwg = gridDim.x * gridDim.y;
  int id = blockIdx.y * gridDim.x + blockIdx.x;
  int swz = (nwg & 7) ? id : ((id & 7) * (nwg >> 3) + (id >> 3));
  const int m0 = (swz / gridDim.x) * 256;
  const int n0 = (swz % gridDim.x) * 256;
  const int bz = blockIdx.z;
  const char* Ab = (const char*)(Ag + (size_t)bz * sA);
  const char* Bb = (const char*)(Bg + (size_t)bz * sB);
  const int t = threadIdx.x;
  const int lane = t & 63;
  const int w = t >> 6;
  const int wm = w >> 2, wn = w & 3;       // 2M x 4N, wave = 128 x 64
  const size_t pA = (size_t)Kd * 2;
  const size_t pB = (size_t)Kd * 2;
  const int nt = Kd >> 6;

  auto Abuf = [&](int par, int h) { return SH + (par * 2 + h) * HSZ; };
  auto Bbuf = [&](int par, int h) { return SH + 4 * HSZ + (par * 2 + h) * HSZ; };

  auto stageH = [&](ushort* ldsb, const char* gb, size_t pitch) {
#pragma unroll
    for (int j = 0; j < 2; ++j) {
      int g = j * 512 + t;
      int r = g >> 3;
      int cb = ((g & 7) << 4) ^ ((r & 7) << 4);
      gload_lds16(gb + (size_t)r * pitch + cb,
                  (char*)ldsb + (size_t)((j * 512 + (t & ~63)) << 4));
    }
  };
  // A half h of tile T -> rows m0+h*128, col T*64 ; B half h -> n0+h*128
  auto stA = [&](int T, int h) {
    stageH(Abuf(T & 1, h), Ab + (size_t)(m0 + h * 128) * pA + (size_t)T * 128, pA);
  };
  auto stB = [&](int T, int h) {
    stageH(Bbuf(T & 1, h), Bb + (size_t)(n0 + h * 128) * pB + (size_t)T * 128, pB);
  };
  auto ldfrag = [&](const ushort* base, int row, int ks) -> bf16x8 {
    int L = row * 128 + ks * 64 + ((lane >> 4) << 4);
    return *(const bf16x8*)((const char*)base + (L ^ ((row & 7) << 4)));
  };

  f32x4 acc[8][4];
#pragma unroll
  for (int i = 0; i < 8; ++i)
#pragma unroll
    for (int j = 0; j < 4; ++j) acc[i][j] = 0.f;

  bf16x8 a0[4][2], a1[4][2];   // A subtiles (rows 0-63 / 64-127 of wave half)
  bf16x8 b[2][2];              // current B subtile (b0 then b1)

// register loads (per wave: its own A-half = wm, B-half = wn>>1)
#define LDA0(Ac)                                                         \
  _Pragma("unroll") for (int mi = 0; mi < 4; ++mi) {                     \
    int r = mi * 16 + (lane & 15);                                       \
    a0[mi][0] = ldfrag(Ac, r, 0); a0[mi][1] = ldfrag(Ac, r, 1);          \
  }
#define LDA1(Ac)                                                         \
  _Pragma("unroll") for (int mi = 0; mi < 4; ++mi) {                     \
    int r = 64 + mi * 16 + (lane & 15);                                  \
    a1[mi][0] = ldfrag(Ac, r, 0); a1[mi][1] = ldfrag(Ac, r, 1);          \
  }
#define LDB(Bc, sub)                                                     \
  _Pragma("unroll") for (int ni = 0; ni < 2; ++ni) {                     \
    int r = (wn & 1) * 64 + ((sub) * 2 + ni) * 16 + (lane & 15);         \
    b[ni][0] = ldfrag(Bc, r, 0); b[ni][1] = ldfrag(Bc, r, 1);            \
  }
// 16-MFMA quadrant: a-array AV (a0/a1), acc row base MB, acc col base NB
#define MF(AV, MB, NB)                                                   \
  __builtin_amdgcn_s_setprio(1);                                         \
  _Pragma("unroll") for (int mi = 0; mi < 4; ++mi)                       \
      _Pragma("unroll") for (int ni = 0; ni < 2; ++ni) {                 \
    if constexpr (MODE == 1) {                                           \
      acc[(MB) + mi][(NB) + ni] =                                        \
          MFMA16(b[ni][0], AV[mi][0], acc[(MB) + mi][(NB) + ni]);        \
      acc[(MB) + mi][(NB) + ni] =                                        \
          MFMA16(b[ni][1], AV[mi][1], acc[(MB) + mi][(NB) + ni]);        \
    } else {                                                             \
      acc[(MB) + mi][(NB) + ni] =                                        \
          MFMA16(AV[mi][0], b[ni][0], acc[(MB) + mi][(NB) + ni]);        \
      acc[(MB) + mi][(NB) + ni] =                                        \
          MFMA16(AV[mi][1], b[ni][1], acc[(MB) + mi][(NB) + ni]);        \
    }                                                                    \
  }                                                                      \
  __builtin_amdgcn_s_setprio(0);

  // ---- prologue: A0(0),A1(0),B0(0),B1(0),A0(1),A1(1); VWAIT(4) ----
  stA(0, 0); stA(0, 1); stB(0, 0); stB(0, 1); stA(1, 0); stA(1, 1);
  VWAIT(4);                                // tile0 resident; A(1) in flight
  BAR();

  for (int tt = 0; tt < nt; ++tt) {
    const ushort* Ac = Abuf(tt & 1, wm);
    const ushort* Bc = Bbuf(tt & 1, wn >> 1);
    // ---- P0: lda0 + ldb0 (12 ds); stage B0(t+1); MFMA Q00 ----
    LDA0(Ac); LDB(Bc, 0);
    if (tt + 1 < nt) stB(tt + 1, 0);
    BAR();
    MF(a0, 0, 0);
    BAR();
    // ---- P1: lda1 (8 ds); stage B1(t+1); MFMA Q10 ----
    LDA1(Ac);
    if (tt + 1 < nt) stB(tt + 1, 1);
    BAR();
    MF(a1, 4, 0);
    BAR();
    // ---- P2: ldb1 (4 ds); stage A0(t+2); MFMA Q11 ----
    LDB(Bc, 1);
    if (tt + 2 < nt) stA(tt + 2, 0);
    BAR();
    MF(a1, 4, 2);
    BAR();
    // ---- P3: stage A1(t+2); VWAIT(4) once/tile; MFMA Q01 ----
    if (tt + 2 < nt) { stA(tt + 2, 1); VWAIT(4); }
    else VWAIT(0);
    BAR();                                 // publishes tile t+1 to all waves
    MF(a0, 0, 2);
    BAR();
  }
#undef LDA0
#undef LDA1
#undef LDB
#undef MF

  if constexpr (MODE == 0) {
    const int seg = n0 >> 10;
    const int n0l = n0 & 1023;
    const float* biasp = seg == 0 ? b0 : b1;
    ushort* Ch = (ushort*)(seg == 0 ? C0 : C1);
#pragma unroll
    for (int mf = 0; mf < 8; ++mf)
#pragma unroll
      for (int nf = 0; nf < 4; ++nf) {
        int gn = n0l + wn * 64 + nf * 16 + (lane & 15);
        float bb = biasp[gn];
#pragma unroll
        for (int r = 0; r < 4; ++r) {
          int gm = m0 + wm * 128 + mf * 16 + (lane >> 4) * 4 + r;
          Ch[(size_t)gm * N + gn] = f2b(acc[mf][nf][r] * scale + bb);
        }
      }
  } else {
    // S (swapped): lane row gm fixed per mf; 4 consecutive gn per reg.
    ushort* Ch = (ushort*)C0 + (size_t)bz * sC;
    float rs[8];
#pragma unroll
    for (int mf = 0; mf < 8; ++mf) rs[mf] = 0.f;
#pragma unroll
    for (int mf = 0; mf < 8; ++mf) {
      int gm = m0 + wm * 128 + mf * 16 + (lane & 15);
#pragma unroll
      for (int nf = 0; nf < 4; ++nf) {
        int gn0 = n0 + wn * 64 + nf * 16 + (lane >> 4) * 4;
        float e0 = __expf(acc[mf][nf][0] * scale);
        float e1 = __expf(acc[mf][nf][1] * scale);
        float e2 = __expf(acc[mf][nf][2] * scale);
        float e3 = __expf(acc[mf][nf][3] * scale);
        rs[mf] += (e0 + e1) + (e2 + e3);
        ushort4 pk;
        pk.x = f2b(e0); pk.y = f2b(e1); pk.z = f2b(e2); pk.w = f2b(e3);
        *(ushort4*)&Ch[(size_t)gm * N + gn0] = pk;
      }
      rs[mf] += __shfl_xor(rs[mf], 16);
      rs[mf] += __shfl_xor(rs[mf], 32);
    }
    __syncthreads();
    float* Lred = (float*)SH;              // [4 wn][256 rows]
#pragma unroll
    for (int mf = 0; mf < 8; ++mf)
      if (lane < 16) Lred[wn * 256 + wm * 128 + mf * 16 + lane] = rs[mf];
    __syncthreads();
    if (t < 256) {
      float s = Lred[t] + Lred[256 + t] + Lred[512 + t] + Lred[768 + t];
      lpart[((size_t)bz * SEQ + m0 + t) * 8 + (n0 >> 8)] = s;
    }
  }
}

__global__ __launch_bounds__(512) void gemm_qk(
    const ushort* __restrict__ Ag, const ushort* __restrict__ Bg,
    void* __restrict__ C0, void* __restrict__ C1,
    const float* __restrict__ b0, const float* __restrict__ b1) {
  gemm256_body<0>(Ag, Bg, C0, C1, b0, b1, nullptr, DIM, DIM, 1.0f, 0, 0, 0);
}
__global__ __launch_bounds__(512) void gemm_s(
    const ushort* __restrict__ Ag, const ushort* __restrict__ Bg,
    void* __restrict__ C0, float* __restrict__ lpart) {
  gemm256_body<1>(Ag, Bg, C0, nullptr, nullptr, nullptr, lpart,
                  SEQ, DIM, 0.03125f, (long)SEQ * DIM, (long)SEQ * DIM,
                  (long)SEQ * SEQ);
}

// ====== 128x256 8-wave TRIPLE-BUFFERED GEMM (2Mx4N, wave 64x64) ======
// (round-9..12 proven body, UNCHANGED)
// BAR1 (WAR) / stage t+2 / VWAIT(12) / BAR2 (RAW) / reads + MFMA.
// MODE 2 (V): unswapped; out transposed to vt[b][d][token] via LDS bounce.
// MODE 3 (PV): SWAPPED mfma; f32x4 coalesced stores, 1 inv/row.
template <int MODE>
__device__ __forceinline__ void gemm_small_body(
    const ushort* __restrict__ Ag, const ushort* __restrict__ Bg,
    void* __restrict__ C0, const float* __restrict__ x0,
    int N, int Kd, long sA, long sB, long sC)
{
  constexpr int ASZ = 128 * 64;
  constexpr int BSZ = 256 * 64;
  __shared__ ushort SH[3 * ASZ + 3 * BSZ]; // 144 KiB

  int nwg = gridDim.x * gridDim.y;
  int id = blockIdx.y * gridDim.x + blockIdx.x;
  int swz = (nwg & 7) ? id : ((id & 7) * (nwg >> 3) + (id >> 3));
  const int m0 = (swz / gridDim.x) * 128;
  const int n0 = (swz % gridDim.x) * 256;
  const int bz = blockIdx.z;
  const char* Ab = (const char*)(Ag + (size_t)bz * sA);
  const char* Bb = (const char*)(Bg + (size_t)bz * sB);
  const int t = threadIdx.x;
  const int lane = t & 63;
  const int w = t >> 6;
  const int wm = w >> 2, wn = w & 3;       // 2M x 4N, wave = 64 x 64
  const size_t pA = (size_t)Kd * 2;
  const size_t pB = (size_t)Kd * 2;
  const int nt = Kd >> 6;

  auto stageH = [&](ushort* ldsb, const char* gb, size_t pitch) {
#pragma unroll
    for (int j = 0; j < 2; ++j) {
      int g = j * 512 + t;
      int r = g >> 3;
      int cb = ((g & 7) << 4) ^ ((r & 7) << 4);
      gload_lds16(gb + (size_t)r * pitch + cb,
                  (char*)ldsb + (size_t)((j * 512 + (t & ~63)) << 4));
    }
  };
  auto ldfrag = [&](const ushort* base, int row, int ks) -> bf16x8 {
    int L = row * 128 + ks * 64 + ((lane >> 4) << 4);
    return *(const bf16x8*)((const char*)base + (L ^ ((row & 7) << 4)));
  };
  auto stageT = [&](int tile) {
    ushort* Abuf = SH + (tile % 3) * ASZ;
    ushort* Bbuf = SH + 3 * ASZ + (tile % 3) * BSZ;
    const size_t ko = (size_t)tile * 128;
    stageH(Abuf, Ab + (size_t)m0 * pA + ko, pA);
    stageH(Bbuf, Bb + (size_t)n0 * pB + ko, pB);
    stageH(Bbuf + 128 * 64, Bb + (size_t)(n0 + 128) * pB + ko, pB);
  };

  f32x4 acc[4][4];
#pragma unroll
  for (int i = 0; i < 4; ++i)
#pragma unroll
    for (int j = 0; j < 4; ++j) acc[i][j] = 0.f;

  bf16x8 a[2][2];
  bf16x8 b[4][2];

  stageT(0);
  stageT(1);

  for (int tt = 0; tt < nt; ++tt) {
    const ushort* Ac = SH + (tt % 3) * ASZ;
    const ushort* Bc = SH + 3 * ASZ + (tt % 3) * BSZ;
    BAR();
    if (tt + 2 < nt) { stageT(tt + 2); VWAIT(12); }
    else if (tt + 1 < nt) VWAIT(6);
    else VWAIT(0);
    BAR();
#pragma unroll
    for (int nf = 0; nf < 4; ++nf) {
      int r = wn * 64 + nf * 16 + (lane & 15);
      b[nf][0] = ldfrag(Bc, r, 0);
      b[nf][1] = ldfrag(Bc, r, 1);
    }
#pragma unroll
    for (int g = 0; g < 2; ++g) {
#pragma unroll
      for (int i = 0; i < 2; ++i) {
        int r = wm * 64 + (g * 2 + i) * 16 + (lane & 15);
        a[i][0] = ldfrag(Ac, r, 0);
        a[i][1] = ldfrag(Ac, r, 1);
      }
      __builtin_amdgcn_s_setprio(1);
#pragma unroll
      for (int i = 0; i < 2; ++i)
#pragma unroll
        for (int nf = 0; nf < 4; ++nf) {
          if constexpr (MODE == 3) {
            acc[g * 2 + i][nf] = MFMA16(b[nf][0], a[i][0], acc[g * 2 + i][nf]);
            acc[g * 2 + i][nf] = MFMA16(b[nf][1], a[i][1], acc[g * 2 + i][nf]);
          } else {
            acc[g * 2 + i][nf] = MFMA16(a[i][0], b[nf][0], acc[g * 2 + i][nf]);
            acc[g * 2 + i][nf] = MFMA16(a[i][1], b[nf][1], acc[g * 2 + i][nf]);
          }
        }
      __builtin_amdgcn_s_setprio(0);
    }
  }

  if constexpr (MODE == 2) {
    __syncthreads();
    const int b_ = m0 >> 11;
    const int tok0 = m0 & 2047;
    ushort* vtb = (ushort*)C0 + (size_t)b_ * DIM * SEQ;
    ushort* T = SH;                        // [256 d][132 tok]
    {
#pragma unroll
      for (int nf = 0; nf < 4; ++nf) {
        int d_loc = wn * 64 + nf * 16 + (lane & 15);
        float bvv = x0[n0 + d_loc];
#pragma unroll
        for (int mf = 0; mf < 4; ++mf) {
          int tok = wm * 64 + mf * 16 + (lane >> 4) * 4;
          ushort4 pk;
          pk.x = f2b(acc[mf][nf][0] + bvv);
          pk.y = f2b(acc[mf][nf][1] + bvv);
          pk.z = f2b(acc[mf][nf][2] + bvv);
          pk.w = f2b(acc[mf][nf][3] + bvv);
          *(ushort4*)&T[d_loc * 132 + tok] = pk;
        }
      }
    }
    __syncthreads();
    {
      int rr = t >> 1, ch = t & 1;
      ushort* dst = vtb + (size_t)(n0 + rr) * SEQ + tok0 + ch * 64;
#pragma unroll
      for (int i = 0; i < 8; ++i)
        *(bf16x8*)(dst + i * 8) = *(const bf16x8*)&T[rr * 132 + ch * 64 + i * 8];
    }
  } else {
    const float* lp = x0 + (size_t)bz * SEQ * 8;
    float* Cf = (float*)C0 + (size_t)bz * sC;
#pragma unroll
    for (int mf = 0; mf < 4; ++mf) {
      int row = m0 + wm * 64 + mf * 16 + (lane & 15);
      const f32x4* q = (const f32x4*)(lp + (size_t)row * 8);
      f32x4 u = q[0] + q[1];
      float inv = 1.f / ((u[0] + u[1]) + (u[2] + u[3]));
#pragma unroll
      for (int nf = 0; nf < 4; ++nf) {
        int gn0 = n0 + wn * 64 + nf * 16 + (lane >> 4) * 4;
        f32x4 o = acc[mf][nf] * inv;
        *(f32x4*)&Cf[(size_t)row * N + gn0] = o;
      }
    }
  }
}

__global__ __launch_bounds__(512) void gemm_v(
    const ushort* __restrict__ Ag, const ushort* __restrict__ Bg,
    void* __restrict__ C0, const float* __restrict__ bv) {
  gemm_small_body<2>(Ag, Bg, C0, bv, DIM, DIM, 0, 0, 0);
}
__global__ __launch_bounds__(512) void gemm_pv(
    const ushort* __restrict__ Ag, const ushort* __restrict__ Bg,
    void* __restrict__ C0, const float* __restrict__ lpart) {
  gemm_small_body<3>(Ag, Bg, C0, lpart, DIM, SEQ,
                     (long)SEQ * SEQ, (long)DIM * SEQ, (long)SEQ * DIM);
}

// ---------------- launcher ----------------
extern "C" void kernel_launch(void* const* d_in, const int* in_sizes, int n_in,
                              void* d_out, int out_size, void* d_ws, size_t ws_size,
                              hipStream_t stream) {
  const float* x  = (const float*)d_in[0];
  const float* Wq = (const float*)d_in[1];
  const float* bq = (const float*)d_in[2];
  const float* Wk = (const float*)d_in[3];
  const float* bk = (const float*)d_in[4];
  const float* Wv = (const float*)d_in[5];
  const float* bv = (const float*)d_in[6];
  float* out = (float*)d_out;

  char* ws = (char*)d_ws;
  // ws layout (bytes), total 90.2 MB:
  //   [0, 32M)      SP  [4][2048][2048] bf16 (xb at [16M,32M) dead by then)
  //   [32M, 38.3M)  wb  (dead after gemm_v) / lpart overlay
  //   [38.3M, ...)  qb | kb | vt  (16M each)
  ushort* xb = (ushort*)(ws + 16777216);
  ushort* wb = (ushort*)(ws + 33554432);
  ushort* qb = (ushort*)(ws + 39845888);
  ushort* kb = (ushort*)(ws + 56623104);
  ushort* vt = (ushort*)(ws + 73400320);
  ushort* SP = (ushort*)(ws);
  float* lpart = (float*)(ws + 33554432);  // [4][2048][8] f32, overlays dead wb

  cvt_all<<<11264, 256, 0, stream>>>(x, Wq, Wk, Wv, xb, wb);
  // Q,K: [8192 x 2048] = X . [Wq;Wk]^T + bias.  256 blocks.
  gemm_qk<<<dim3(8, 32, 1), 512, 0, stream>>>(xb, wb, qb, kb, bq, bk);
  // V: [8192 x 1024] = X . Wv^T + bias, transposed to vt.  256 blocks (4x64).
  gemm_v<<<dim3(4, 64, 1), 512, 0, stream>>>(xb, wb + 2097152, vt, bv);
  // P = exp(Q K^T / 32) -> SP (+ row partial sums -> lpart).  256 blocks.
  gemm_s<<<dim3(8, 8, 4), 512, 0, stream>>>(qb, kb, SP, lpart);
  // O = (P V) / rowsum.  256 blocks (4x16x4).
  gemm_pv<<<dim3(4, 16, 4), 512, 0, stream>>>(SP, vt, out, lpart);
}